// Round 12
// baseline (127.464 us; speedup 1.0000x reference)
//
#include <hip/hip_runtime.h>
#include <hip/hip_bf16.h>

typedef __attribute__((ext_vector_type(8))) short bf16x8;
typedef __attribute__((ext_vector_type(4))) float f32x4;

#define K_DIM 1024
#define M_PROJ 16384   // 64*256
#define NBATCH 64
#define SEQ 256

static __device__ inline unsigned short bf16_bits(float f) {
    __hip_bfloat16 h = __float2bfloat16(f);
    return *reinterpret_cast<unsigned short*>(&h);
}

// async global->LDS, 16B per lane; LDS dest wave-uniform (HW adds lane*16)
#define GLOAD16(g, l) __builtin_amdgcn_global_load_lds(                          \
    (__attribute__((address_space(1))) void*)(g),                                \
    (__attribute__((address_space(3))) void*)(l), 16, 0, 0)

// ---------------------------------------------------------------------------
// prep: blocks 0..511   -> Waw = bf16(Wa * w), u[row] = Wa[row].(w*bb)
//       blocks 512..1023-> Wb16 = bf16(Wb),   v[row] = Wb[row].(w*ba)
//       block 1024      -> c = sum w*ba*bb
//       block 1025      -> zero per-batch handshake counters (each replay)
// ---------------------------------------------------------------------------
__global__ __launch_bounds__(256) void prep(const float* __restrict__ Wa,
                                            const float* __restrict__ Wb,
                                            const float* __restrict__ w,
                                            const float* __restrict__ ba,
                                            const float* __restrict__ bb,
                                            unsigned short* __restrict__ Waw,
                                            unsigned short* __restrict__ Wb16,
                                            float* __restrict__ u,
                                            float* __restrict__ v,
                                            float* __restrict__ c,
                                            unsigned int* __restrict__ counters)
{
    __shared__ float psum[4];
    const int blk = blockIdx.x;
    const int t = threadIdx.x;

    if (blk < 1024) {
        const int isA = (blk < 512);
        const int r  = (isA ? blk : blk - 512) * 2 + (t >> 7);
        const int c8 = (t & 127) * 8;
        const float* in  = isA ? Wa : Wb;
        const float* bv  = isA ? bb : ba;
        unsigned short* o = isA ? Waw : Wb16;

        const float* xp = &in[(size_t)r * K_DIM + c8];
        float4 v0 = *(const float4*)xp;
        float4 v1 = *(const float4*)(xp + 4);
        float4 w0 = *(const float4*)&w[c8];
        float4 w1 = *(const float4*)&w[c8 + 4];
        float4 b0 = *(const float4*)&bv[c8];
        float4 b1 = *(const float4*)&bv[c8 + 4];

        float part = v0.x * w0.x * b0.x + v0.y * w0.y * b0.y
                   + v0.z * w0.z * b0.z + v0.w * w0.w * b0.w
                   + v1.x * w1.x * b1.x + v1.y * w1.y * b1.y
                   + v1.z * w1.z * b1.z + v1.w * w1.w * b1.w;

        if (isA) {
            v0.x *= w0.x; v0.y *= w0.y; v0.z *= w0.z; v0.w *= w0.w;
            v1.x *= w1.x; v1.y *= w1.y; v1.z *= w1.z; v1.w *= w1.w;
        }
        unsigned short uo[8];
        uo[0] = bf16_bits(v0.x); uo[1] = bf16_bits(v0.y); uo[2] = bf16_bits(v0.z); uo[3] = bf16_bits(v0.w);
        uo[4] = bf16_bits(v1.x); uo[5] = bf16_bits(v1.y); uo[6] = bf16_bits(v1.z); uo[7] = bf16_bits(v1.w);
        *reinterpret_cast<uint4*>(&o[(size_t)r * K_DIM + c8]) = *reinterpret_cast<uint4*>(uo);

#pragma unroll
        for (int off = 32; off; off >>= 1) part += __shfl_down(part, off);
        if ((t & 63) == 0) psum[t >> 6] = part;
        __syncthreads();
        if ((t & 127) == 0) {
            const float s = psum[t >> 6] + psum[(t >> 6) + 1];
            if (isA) u[r] = s; else v[r] = s;
        }
        return;
    }
    if (blk == 1025) {
        if (t < NBATCH) counters[t] = 0u;
        return;
    }
    // blk == 1024: c
    const int d0 = t * 4;
    float4 ww = *(const float4*)&w[d0];
    float4 b1 = *(const float4*)&ba[d0];
    float4 b2 = *(const float4*)&bb[d0];
    float part = ww.x * b1.x * b2.x + ww.y * b1.y * b2.y
               + ww.z * b1.z * b2.z + ww.w * b1.w * b2.w;
#pragma unroll
    for (int off = 32; off; off >>= 1) part += __shfl_down(part, off);
    if ((t & 63) == 0) psum[t >> 6] = part;
    __syncthreads();
    if (t == 0) *c = (psum[0] + psum[1]) + (psum[2] + psum[3]);
}

// ---------------------------------------------------------------------------
// X [16384][1024] f32 -> bf16; also rowdot[r] = sum_d X[r][d]*dvec[d].
// ---------------------------------------------------------------------------
__global__ __launch_bounds__(256) void conv_rows(const float* __restrict__ X,
                                                 const float* __restrict__ dvec,
                                                 unsigned short* __restrict__ out,
                                                 float* __restrict__ rowdot)
{
    __shared__ float psum[4];
    const int t = threadIdx.x;
    const int r = blockIdx.x * 2 + (t >> 7);
    const int c8 = (t & 127) * 8;

    const float* xp = &X[(size_t)r * K_DIM + c8];
    float4 v0 = *(const float4*)xp;
    float4 v1 = *(const float4*)(xp + 4);
    float4 u0 = *(const float4*)&dvec[c8];
    float4 u1 = *(const float4*)&dvec[c8 + 4];
    float part = v0.x * u0.x + v0.y * u0.y + v0.z * u0.z + v0.w * u0.w
               + v1.x * u1.x + v1.y * u1.y + v1.z * u1.z + v1.w * u1.w;

    unsigned short uo[8];
    uo[0] = bf16_bits(v0.x); uo[1] = bf16_bits(v0.y); uo[2] = bf16_bits(v0.z); uo[3] = bf16_bits(v0.w);
    uo[4] = bf16_bits(v1.x); uo[5] = bf16_bits(v1.y); uo[6] = bf16_bits(v1.z); uo[7] = bf16_bits(v1.w);
    *reinterpret_cast<uint4*>(&out[(size_t)r * K_DIM + c8]) = *reinterpret_cast<uint4*>(uo);

#pragma unroll
    for (int off = 32; off; off >>= 1) part += __shfl_down(part, off);
    if ((t & 63) == 0) psum[t >> 6] = part;
    __syncthreads();
    if ((t & 127) == 0) rowdot[r] = psum[(t >> 6)] + psum[(t >> 6) + 1];
}

// ---------------------------------------------------------------------------
// Mt[q][p] = sum_d Wb16[q][d] * Waw[p][d]   (bf16 out, 128x128 tiles)
// ---------------------------------------------------------------------------
__global__ __launch_bounds__(256) void mt_gemm(const __hip_bfloat16* __restrict__ Wb16,
                                               const __hip_bfloat16* __restrict__ Waw,
                                               unsigned short* __restrict__ Mt)
{
    __shared__ __align__(16) unsigned short As[128][32];
    __shared__ __align__(16) unsigned short Bs[128][32];

    const int tid  = threadIdx.x;
    const int lane = tid & 63;
    const int wave = tid >> 6;
    const int q0 = blockIdx.x * 128;
    const int p0 = blockIdx.y * 128;
    const int wr = (wave >> 1) * 64;
    const int wc = (wave & 1) * 64;

    const __hip_bfloat16* Arow = Wb16 + (size_t)q0 * K_DIM;
    const __hip_bfloat16* Brow = Waw + (size_t)p0 * K_DIM;

    f32x4 acc[4][4];
#pragma unroll
    for (int i = 0; i < 4; ++i)
#pragma unroll
        for (int j = 0; j < 4; ++j) acc[i][j] = f32x4{0.f, 0.f, 0.f, 0.f};

    const int lrow = lane & 15;
    const int kq   = (lane >> 4) * 8;

    for (int k0 = 0; k0 < K_DIM; k0 += 32) {
        __syncthreads();
#pragma unroll
        for (int it = 0; it < 2; ++it) {
            const int chunk = (it * 4 + wave) * 64 + lane;
            const int row = chunk >> 2;
            const int col = (chunk & 3) * 8;
            GLOAD16(Arow + (size_t)row * K_DIM + k0 + col,
                    reinterpret_cast<char*>(&As[0][0]) + (it * 4 + wave) * 1024);
        }
#pragma unroll
        for (int it = 0; it < 2; ++it) {
            const int chunk = (it * 4 + wave) * 64 + lane;
            const int row = chunk >> 2;
            const int col = (chunk & 3) * 8;
            GLOAD16(Brow + (size_t)row * K_DIM + k0 + col,
                    reinterpret_cast<char*>(&Bs[0][0]) + (it * 4 + wave) * 1024);
        }
        __syncthreads();

        bf16x8 af[4], bfr[4];
#pragma unroll
        for (int f = 0; f < 4; ++f) {
            af[f]  = *reinterpret_cast<const bf16x8*>(&As[wr + f * 16 + lrow][kq]);
            bfr[f] = *reinterpret_cast<const bf16x8*>(&Bs[wc + f * 16 + lrow][kq]);
        }
#pragma unroll
        for (int i = 0; i < 4; ++i)
#pragma unroll
            for (int j = 0; j < 4; ++j)
                acc[i][j] = __builtin_amdgcn_mfma_f32_16x16x32_bf16(bfr[j], af[i], acc[i][j], 0, 0, 0);
    }

#pragma unroll
    for (int ii = 0; ii < 4; ++ii) {
        const int q = q0 + wr + ii * 16 + lrow;
#pragma unroll
        for (int jj = 0; jj < 4; ++jj) {
            const int pb = p0 + wc + jj * 16 + (lane >> 4) * 4;
            unsigned short uo[4];
            uo[0] = bf16_bits(acc[ii][jj][0]);
            uo[1] = bf16_bits(acc[ii][jj][1]);
            uo[2] = bf16_bits(acc[ii][jj][2]);
            uo[3] = bf16_bits(acc[ii][jj][3]);
            *(ushort4*)&Mt[(size_t)q * K_DIM + pb] = *(ushort4*)uo;
        }
    }
}

// ---------------------------------------------------------------------------
// 8-phase 256x256 GEMM (round-5 K-loop, 0 bank conflicts) with operand-swapped
// MFMA + LDS-roundtrip coalesced epilogue (full 64B-granule output stores).
// ---------------------------------------------------------------------------
__global__ __launch_bounds__(512, 2) void proj_gemm256(
    const __hip_bfloat16* __restrict__ A,   // [M][1024]
    const __hip_bfloat16* __restrict__ Wt,  // [1024][1024]  (row n, col k)
    __hip_bfloat16* __restrict__ out)
{
    __shared__ __align__(16) unsigned short lds[2][4][128 * 64];

    const int tid  = threadIdx.x;
    const int lane = tid & 63;
    const int w    = tid >> 6;
    const int wr   = w >> 2;
    const int wc   = w & 3;
    const int m0 = blockIdx.x * 256;
    const int n0 = blockIdx.y * 256;

    const int c1 = w * 128 + lane, c2 = c1 + 64;
    const int r1 = c1 >> 3, r2 = c2 >> 3;
    const int k1 = (c1 & 7) ^ (r1 & 7);
    const int k2 = (c2 & 7) ^ (r2 & 7);

    const int lrow = lane & 15;
    const int kq0  = (((lane >> 4) + 0) ^ (lane & 7)) * 16;
    const int kq1  = (((lane >> 4) + 4) ^ (lane & 7)) * 16;

#define STG(SRC, RB, KB, BUF, REG)                                               \
    {                                                                            \
        GLOAD16((SRC) + (size_t)((RB) + r1) * K_DIM + (KB) + k1 * 8,             \
                (char*)(&lds[BUF][REG][0]) + w * 2048);                          \
        GLOAD16((SRC) + (size_t)((RB) + r2) * K_DIM + (KB) + k2 * 8,             \
                (char*)(&lds[BUF][REG][0]) + w * 2048 + 1024);                   \
    }

    f32x4 acc[8][4];
#pragma unroll
    for (int i = 0; i < 8; ++i)
#pragma unroll
        for (int j = 0; j < 4; ++j) acc[i][j] = f32x4{0.f, 0.f, 0.f, 0.f};

    STG(A,  m0,       0, 0, 0); STG(A,  m0 + 128,  0, 0, 1);
    STG(Wt, n0,       0, 0, 2); STG(Wt, n0 + 128,  0, 0, 3);
    STG(A,  m0,      64, 1, 0); STG(A,  m0 + 128, 64, 1, 1);
    asm volatile("s_waitcnt vmcnt(4)" ::: "memory");
    __builtin_amdgcn_sched_barrier(0);
    __builtin_amdgcn_s_barrier();

#define KTILE(CUR, NXT, T)                                                       \
    {                                                                            \
        const int kb1 = (((T) + 1) & 15) << 6;                                   \
        const int kb2 = (((T) + 2) & 15) << 6;                                   \
        const char* Ab = (const char*)(&lds[CUR][wr][0]);                        \
        const char* Bb = (const char*)(&lds[CUR][2 + (wc >> 1)][0])              \
                         + (wc & 1) * 8192;                                      \
        bf16x8 af[4][2], bfr[4][2];                                              \
        _Pragma("unroll")                                                        \
        for (int mi = 0; mi < 4; ++mi) {                                         \
            af[mi][0] = *(const bf16x8*)(Ab + mi * 2048 + lrow * 128 + kq0);     \
            af[mi][1] = *(const bf16x8*)(Ab + mi * 2048 + lrow * 128 + kq1);     \
        }                                                                        \
        _Pragma("unroll")                                                        \
        for (int nj = 0; nj < 2; ++nj) {                                         \
            bfr[nj][0] = *(const bf16x8*)(Bb + nj * 2048 + lrow * 128 + kq0);    \
            bfr[nj][1] = *(const bf16x8*)(Bb + nj * 2048 + lrow * 128 + kq1);    \
        }                                                                        \
        STG(Wt, n0, kb1, NXT, 2);                                                \
        __builtin_amdgcn_sched_barrier(0);                                       \
        __builtin_amdgcn_s_barrier();                                            \
        asm volatile("s_waitcnt lgkmcnt(0)" ::: "memory");                       \
        __builtin_amdgcn_sched_barrier(0);                                       \
        __builtin_amdgcn_s_setprio(1);                                           \
        _Pragma("unroll")                                                        \
        for (int mi = 0; mi < 4; ++mi)                                           \
            _Pragma("unroll")                                                    \
            for (int nj = 0; nj < 2; ++nj) {                                     \
                acc[mi][nj] = __builtin_amdgcn_mfma_f32_16x16x32_bf16(           \
                    bfr[nj][0], af[mi][0], acc[mi][nj], 0, 0, 0);                \
                acc[mi][nj] = __builtin_amdgcn_mfma_f32_16x16x32_bf16(           \
                    bfr[nj][1], af[mi][1], acc[mi][nj], 0, 0, 0);                \
            }                                                                    \
        __builtin_amdgcn_s_setprio(0);                                           \
        __builtin_amdgcn_sched_barrier(0);                                       \
        __builtin_amdgcn_s_barrier();                                            \
        _Pragma("unroll")                                                        \
        for (int nj = 2; nj < 4; ++nj) {                                         \
            bfr[nj][0] = *(const bf16x8*)(Bb + nj * 2048 + lrow * 128 + kq0);    \
            bfr[nj][1] = *(const bf16x8*)(Bb + nj * 2048 + lrow * 128 + kq1);    \
        }                                                                        \
        STG(Wt, n0 + 128, kb1, NXT, 3);                                          \
        __builtin_amdgcn_sched_barrier(0);                                       \
        __builtin_amdgcn_s_barrier();                                            \
        asm volatile("s_waitcnt lgkmcnt(0)" ::: "memory");                       \
        __builtin_amdgcn_sched_barrier(0);                                       \
        __builtin_amdgcn_s_setprio(1);                                           \
        _Pragma("unroll")                                                        \
        for (int mi = 0; mi < 4; ++mi)                                           \
            _Pragma("unroll")                                                    \
            for (int nj = 2; nj < 4; ++nj) {                                     \
                acc[mi][nj] = __builtin_amdgcn_mfma_f32_16x16x32_bf16(           \
                    bfr[nj][0], af[mi][0], acc[mi][nj], 0, 0, 0);                \
                acc[mi][nj] = __builtin_amdgcn_mfma_f32_16x16x32_bf16(           \
                    bfr[nj][1], af[mi][1], acc[mi][nj], 0, 0, 0);                \
            }                                                                    \
        __builtin_amdgcn_s_setprio(0);                                           \
        __builtin_amdgcn_sched_barrier(0);                                       \
        __builtin_amdgcn_s_barrier();                                            \
        _Pragma("unroll")                                                        \
        for (int mi = 0; mi < 4; ++mi) {                                         \
            af[mi][0] = *(const bf16x8*)(Ab + 8192 + mi * 2048 + lrow * 128 + kq0);\
            af[mi][1] = *(const bf16x8*)(Ab + 8192 + mi * 2048 + lrow * 128 + kq1);\
        }                                                                        \
        __builtin_amdgcn_sched_barrier(0);                                       \
        __builtin_amdgcn_s_barrier();                                            \
        asm volatile("s_waitcnt lgkmcnt(0)" ::: "memory");                       \
        __builtin_amdgcn_sched_barrier(0);                                       \
        __builtin_amdgcn_s_setprio(1);                                           \
        _Pragma("unroll")                                                        \
        for (int mi = 0; mi < 4; ++mi)                                           \
            _Pragma("unroll")                                                    \
            for (int nj = 0; nj < 2; ++nj) {                                     \
                acc[4 + mi][nj] = __builtin_amdgcn_mfma_f32_16x16x32_bf16(       \
                    bfr[nj][0], af[mi][0], acc[4 + mi][nj], 0, 0, 0);            \
                acc[4 + mi][nj] = __builtin_amdgcn_mfma_f32_16x16x32_bf16(       \
                    bfr[nj][1], af[mi][1], acc[4 + mi][nj], 0, 0, 0);            \
            }                                                                    \
        __builtin_amdgcn_s_setprio(0);                                           \
        __builtin_amdgcn_sched_barrier(0);                                       \
        __builtin_amdgcn_s_barrier();                                            \
        STG(A, m0,       kb2, CUR, 0);                                           \
        STG(A, m0 + 128, kb2, CUR, 1);                                           \
        __builtin_amdgcn_sched_barrier(0);                                       \
        __builtin_amdgcn_s_barrier();                                            \
        __builtin_amdgcn_s_setprio(1);                                           \
        _Pragma("unroll")                                                        \
        for (int mi = 0; mi < 4; ++mi)                                           \
            _Pragma("unroll")                                                    \
            for (int nj = 2; nj < 4; ++nj) {                                     \
                acc[4 + mi][nj] = __builtin_amdgcn_mfma_f32_16x16x32_bf16(       \
                    bfr[nj][0], af[mi][0], acc[4 + mi][nj], 0, 0, 0);            \
                acc[4 + mi][nj] = __builtin_amdgcn_mfma_f32_16x16x32_bf16(       \
                    bfr[nj][1], af[mi][1], acc[4 + mi][nj], 0, 0, 0);            \
            }                                                                    \
        __builtin_amdgcn_s_setprio(0);                                           \
        asm volatile("s_waitcnt vmcnt(4)" ::: "memory");                         \
        __builtin_amdgcn_sched_barrier(0);                                       \
        __builtin_amdgcn_s_barrier();                                            \
    }

    for (int tt = 0; tt < 8; ++tt) {
        const int t0 = tt * 2;
        KTILE(0, 1, t0);
        KTILE(1, 0, t0 + 1);
    }
#undef KTILE
#undef STG

    // ---- coalesced epilogue via LDS roundtrip ----
    asm volatile("s_waitcnt vmcnt(0)" ::: "memory");
    __builtin_amdgcn_sched_barrier(0);
    __builtin_amdgcn_s_barrier();
    char* eb = (char*)(&lds[0][0][0]);
#pragma unroll
    for (int mi8 = 0; mi8 < 8; ++mi8) {
        const int ml = wr * 128 + (mi8 >> 2) * 64 + (mi8 & 3) * 16 + lrow;
#pragma unroll
        for (int nj = 0; nj < 4; ++nj) {
            const int nl = wc * 64 + nj * 16 + (lane >> 4) * 4;
            unsigned short uo[4];
            uo[0] = bf16_bits(acc[mi8][nj][0]);
            uo[1] = bf16_bits(acc[mi8][nj][1]);
            uo[2] = bf16_bits(acc[mi8][nj][2]);
            uo[3] = bf16_bits(acc[mi8][nj][3]);
            const int vv = nl >> 3;
            *(ushort4*)(eb + ml * 512 + ((vv ^ (ml & 7)) * 16) + ((nl >> 2) & 1) * 8)
                = *(ushort4*)uo;
        }
    }
    __syncthreads();
#pragma unroll
    for (int p = 0; p < 2; ++p) {
        const int ml = p * 128 + (tid >> 2);
#pragma unroll
        for (int it = 0; it < 8; ++it) {
            const int vv = it * 4 + (tid & 3);
            uint4 val = *(const uint4*)(eb + ml * 512 + ((vv ^ (ml & 7)) * 16));
            *(uint4*)&out[(size_t)(m0 + ml) * K_DIM + n0 + vv * 8] = val;
        }
    }
}

// ---------------------------------------------------------------------------
// Scores (128x128 tiles) + exp + FUSED normalization. 1-D grid: id = b + 64*q,
// so the 4 blocks of batch b are ids == b (mod 8) -> SAME XCD -> panel reuse
// in that XCD's L2 AND an L2-local partial-sum handshake (agent atomics).
// Deterministic: fixed-order 4-partial sum; counters zeroed by prep each call.
// ---------------------------------------------------------------------------
__global__ __launch_bounds__(256) void score_gemm(const __hip_bfloat16* __restrict__ T,
                                                  const __hip_bfloat16* __restrict__ Bbf,
                                                  const float* __restrict__ alpha,
                                                  const float* __restrict__ beta,
                                                  const float* __restrict__ cptr,
                                                  const float* __restrict__ wbias,
                                                  float* __restrict__ out,
                                                  float* __restrict__ partials,
                                                  unsigned int* __restrict__ counters)
{
    __shared__ __align__(16) unsigned short As[128][32];
    __shared__ __align__(16) unsigned short Bs[128][32];
    __shared__ float psum[4];
    __shared__ float inv_s;

    const int tid  = threadIdx.x;
    const int lane = tid & 63;
    const int wave = tid >> 6;
    const int b  = blockIdx.x & 63;
    const int q  = blockIdx.x >> 6;       // 0..3
    const int i0 = (q >> 1) * 128;
    const int j0 = (q & 1) * 128;
    const int wr = (wave >> 1) * 64;
    const int wc = (wave & 1) * 64;

    const __hip_bfloat16* Arow = T + (size_t)(b * SEQ + i0) * K_DIM;
    const __hip_bfloat16* Brow = Bbf + (size_t)(b * SEQ + j0) * K_DIM;

    f32x4 acc[4][4];
#pragma unroll
    for (int i = 0; i < 4; ++i)
#pragma unroll
        for (int j = 0; j < 4; ++j) acc[i][j] = f32x4{0.f, 0.f, 0.f, 0.f};

    const int lrow = lane & 15;
    const int kq   = (lane >> 4) * 8;

    for (int k0 = 0; k0 < K_DIM; k0 += 32) {
        __syncthreads();
#pragma unroll
        for (int it = 0; it < 2; ++it) {
            const int chunk = (it * 4 + wave) * 64 + lane;
            const int row = chunk >> 2;
            const int col = (chunk & 3) * 8;
            GLOAD16(Arow + (size_t)row * K_DIM + k0 + col,
                    reinterpret_cast<char*>(&As[0][0]) + (it * 4 + wave) * 1024);
        }
#pragma unroll
        for (int it = 0; it < 2; ++it) {
            const int chunk = (it * 4 + wave) * 64 + lane;
            const int row = chunk >> 2;
            const int col = (chunk & 3) * 8;
            GLOAD16(Brow + (size_t)row * K_DIM + k0 + col,
                    reinterpret_cast<char*>(&Bs[0][0]) + (it * 4 + wave) * 1024);
        }
        __syncthreads();

        bf16x8 af[4], bfr[4];
#pragma unroll
        for (int f = 0; f < 4; ++f) {
            af[f]  = *reinterpret_cast<const bf16x8*>(&As[wr + f * 16 + lrow][kq]);
            bfr[f] = *reinterpret_cast<const bf16x8*>(&Bs[wc + f * 16 + lrow][kq]);
        }
#pragma unroll
        for (int i = 0; i < 4; ++i)
#pragma unroll
            for (int j = 0; j < 4; ++j)
                acc[i][j] = __builtin_amdgcn_mfma_f32_16x16x32_bf16(bfr[j], af[i], acc[i][j], 0, 0, 0);
    }

    // exp in registers + local sum
    const float cwb = *cptr + *wbias;
    float lsum = 0.f;
#pragma unroll
    for (int ii = 0; ii < 4; ++ii) {
        const int i = i0 + wr + ii * 16 + lrow;
        const float av = alpha[b * SEQ + i] + cwb;
#pragma unroll
        for (int jj = 0; jj < 4; ++jj) {
            const int jb = j0 + wc + jj * 16 + (lane >> 4) * 4;
            const float4 bv = *(const float4*)&beta[b * SEQ + jb];
            acc[ii][jj][0] = __expf(acc[ii][jj][0] + av + bv.x);
            acc[ii][jj][1] = __expf(acc[ii][jj][1] + av + bv.y);
            acc[ii][jj][2] = __expf(acc[ii][jj][2] + av + bv.z);
            acc[ii][jj][3] = __expf(acc[ii][jj][3] + av + bv.w);
            lsum += (acc[ii][jj][0] + acc[ii][jj][1]) + (acc[ii][jj][2] + acc[ii][jj][3]);
        }
    }
#pragma unroll
    for (int off = 32; off; off >>= 1) lsum += __shfl_down(lsum, off);
    if (lane == 0) psum[wave] = lsum;
    __syncthreads();

    // publish partial; L2-local handshake among the 4 same-XCD siblings
    if (tid == 0) {
        const float my = (psum[0] + psum[1]) + (psum[2] + psum[3]);
        __hip_atomic_store(&partials[b * 4 + q], my, __ATOMIC_RELEASE, __HIP_MEMORY_SCOPE_AGENT);
        __hip_atomic_fetch_add(&counters[b], 1u, __ATOMIC_RELEASE, __HIP_MEMORY_SCOPE_AGENT);
        while (__hip_atomic_load(&counters[b], __ATOMIC_ACQUIRE, __HIP_MEMORY_SCOPE_AGENT) < 4u)
            __builtin_amdgcn_s_sleep(1);
        const float p0 = __hip_atomic_load(&partials[b * 4 + 0], __ATOMIC_RELAXED, __HIP_MEMORY_SCOPE_AGENT);
        const float p1 = __hip_atomic_load(&partials[b * 4 + 1], __ATOMIC_RELAXED, __HIP_MEMORY_SCOPE_AGENT);
        const float p2 = __hip_atomic_load(&partials[b * 4 + 2], __ATOMIC_RELAXED, __HIP_MEMORY_SCOPE_AGENT);
        const float p3 = __hip_atomic_load(&partials[b * 4 + 3], __ATOMIC_RELAXED, __HIP_MEMORY_SCOPE_AGENT);
        inv_s = 1.0f / (((p0 + p1) + p2) + p3);
    }
    __syncthreads();
    const float inv = inv_s;

    // single normalized store
#pragma unroll
    for (int ii = 0; ii < 4; ++ii) {
        const int i = i0 + wr + ii * 16 + lrow;
#pragma unroll
        for (int jj = 0; jj < 4; ++jj) {
            const int jb = j0 + wc + jj * 16 + (lane >> 4) * 4;
            float4 e;
            e.x = acc[ii][jj][0] * inv;
            e.y = acc[ii][jj][1] * inv;
            e.z = acc[ii][jj][2] * inv;
            e.w = acc[ii][jj][3] * inv;
            *(float4*)&out[(size_t)b * (SEQ * SEQ) + (size_t)i * SEQ + jb] = e;
        }
    }
}

extern "C" void kernel_launch(void* const* d_in, const int* in_sizes, int n_in,
                              void* d_out, int out_size, void* d_ws, size_t ws_size,
                              hipStream_t stream)
{
    const float* a     = (const float*)d_in[0];
    const float* b     = (const float*)d_in[1];
    const float* Wa    = (const float*)d_in[2];
    const float* ba    = (const float*)d_in[3];
    const float* Wb    = (const float*)d_in[4];
    const float* bb    = (const float*)d_in[5];
    const float* w     = (const float*)d_in[6];
    const float* wbias = (const float*)d_in[7];
    float* out = (float*)d_out;

    char* wsb = (char*)d_ws;
    unsigned short* Waw   = (unsigned short*)(wsb);                       // 2MB
    unsigned short* Wb16  = (unsigned short*)(wsb + (size_t)2097152);     // 2MB
    unsigned short* Mt    = (unsigned short*)(wsb + (size_t)4194304);     // 2MB
    float* u              = (float*)(wsb + (size_t)6291456);              // 4KB
    float* v              = (float*)(wsb + (size_t)6291456 + 4096);       // 4KB
    float* c              = (float*)(wsb + (size_t)6291456 + 8192);       // 4B
    float* alpha          = (float*)(wsb + (size_t)6291456 + 16384);      // 64KB
    float* beta           = (float*)(wsb + (size_t)6291456 + 16384 + 65536); // 64KB
    float* partials       = (float*)(wsb + (size_t)6291456 + 16384 + 131072); // 1KB
    unsigned int* counters= (unsigned int*)(wsb + (size_t)6291456 + 16384 + 131072 + 1024); // 256B
    unsigned short* ab16  = (unsigned short*)(wsb + (size_t)8388608);     // 32MB (a then b)
    unsigned short* Tbuf  = (unsigned short*)(wsb + (size_t)41943040);    // 32MB

    // 1. weight converts + u/v/c + counter zeroing (one launch)
    prep<<<1026, 256, 0, stream>>>(Wa, Wb, w, ba, bb, Waw, Wb16, u, v, c, counters);
    // 2. Mt = (Wa*w) . Wb^T, transposed-stored [q][p]
    mt_gemm<<<dim3(8, 8), 256, 0, stream>>>((const __hip_bfloat16*)Wb16,
                                            (const __hip_bfloat16*)Waw, Mt);
    // 3. a -> bf16 (+alpha = a.u)
    conv_rows<<<M_PROJ / 2, 256, 0, stream>>>(a, u, ab16, alpha);
    // 4. T = a_bf16 @ Mt^T
    const dim3 pgrid(M_PROJ / 256, K_DIM / 256);
    proj_gemm256<<<pgrid, 512, 0, stream>>>((const __hip_bfloat16*)ab16,
                                            (const __hip_bfloat16*)Mt,
                                            (__hip_bfloat16*)Tbuf);
    // 5. b -> bf16 (+beta = b.v)  — reuses ab16
    conv_rows<<<M_PROJ / 2, 256, 0, stream>>>(b, v, ab16, beta);
    // 6. scores + exp + fused normalize (XCD-grouped 1-D grid, L2-local handshake)
    score_gemm<<<256, 256, 0, stream>>>((const __hip_bfloat16*)Tbuf,
                                        (const __hip_bfloat16*)ab16,
                                        alpha, beta, c, wbias, out, partials, counters);
}

// Round 13
// 126.370 us; speedup vs baseline: 1.0087x; 1.0087x over previous
//
#include <hip/hip_runtime.h>
#include <hip/hip_bf16.h>

typedef __attribute__((ext_vector_type(8))) short bf16x8;
typedef __attribute__((ext_vector_type(4))) float f32x4;

#define K_DIM 1024
#define M_PROJ 16384   // 64*256
#define NBATCH 64
#define SEQ 256

static __device__ inline unsigned short bf16_bits(float f) {
    __hip_bfloat16 h = __float2bfloat16(f);
    return *reinterpret_cast<unsigned short*>(&h);
}

// async global->LDS, 16B per lane; LDS dest wave-uniform (HW adds lane*16)
#define GLOAD16(g, l) __builtin_amdgcn_global_load_lds(                          \
    (__attribute__((address_space(1))) void*)(g),                                \
    (__attribute__((address_space(3))) void*)(l), 16, 0, 0)

// ---------------------------------------------------------------------------
// prep: blocks 0..511   -> Waw = bf16(Wa * w), u[row] = Wa[row].(w*bb)
//       blocks 512..1023-> Wb16 = bf16(Wb),   v[row] = Wb[row].(w*ba)
//       block 1024      -> c = sum w*ba*bb
// ---------------------------------------------------------------------------
__global__ __launch_bounds__(256) void prep(const float* __restrict__ Wa,
                                            const float* __restrict__ Wb,
                                            const float* __restrict__ w,
                                            const float* __restrict__ ba,
                                            const float* __restrict__ bb,
                                            unsigned short* __restrict__ Waw,
                                            unsigned short* __restrict__ Wb16,
                                            float* __restrict__ u,
                                            float* __restrict__ v,
                                            float* __restrict__ c)
{
    __shared__ float psum[4];
    const int blk = blockIdx.x;
    const int t = threadIdx.x;

    if (blk < 1024) {
        const int isA = (blk < 512);
        const int r  = (isA ? blk : blk - 512) * 2 + (t >> 7);
        const int c8 = (t & 127) * 8;
        const float* in  = isA ? Wa : Wb;
        const float* bv  = isA ? bb : ba;
        unsigned short* o = isA ? Waw : Wb16;

        const float* xp = &in[(size_t)r * K_DIM + c8];
        float4 v0 = *(const float4*)xp;
        float4 v1 = *(const float4*)(xp + 4);
        float4 w0 = *(const float4*)&w[c8];
        float4 w1 = *(const float4*)&w[c8 + 4];
        float4 b0 = *(const float4*)&bv[c8];
        float4 b1 = *(const float4*)&bv[c8 + 4];

        float part = v0.x * w0.x * b0.x + v0.y * w0.y * b0.y
                   + v0.z * w0.z * b0.z + v0.w * w0.w * b0.w
                   + v1.x * w1.x * b1.x + v1.y * w1.y * b1.y
                   + v1.z * w1.z * b1.z + v1.w * w1.w * b1.w;

        if (isA) {
            v0.x *= w0.x; v0.y *= w0.y; v0.z *= w0.z; v0.w *= w0.w;
            v1.x *= w1.x; v1.y *= w1.y; v1.z *= w1.z; v1.w *= w1.w;
        }
        unsigned short uo[8];
        uo[0] = bf16_bits(v0.x); uo[1] = bf16_bits(v0.y); uo[2] = bf16_bits(v0.z); uo[3] = bf16_bits(v0.w);
        uo[4] = bf16_bits(v1.x); uo[5] = bf16_bits(v1.y); uo[6] = bf16_bits(v1.z); uo[7] = bf16_bits(v1.w);
        *reinterpret_cast<uint4*>(&o[(size_t)r * K_DIM + c8]) = *reinterpret_cast<uint4*>(uo);

#pragma unroll
        for (int off = 32; off; off >>= 1) part += __shfl_down(part, off);
        if ((t & 63) == 0) psum[t >> 6] = part;
        __syncthreads();
        if ((t & 127) == 0) {
            const float s = psum[t >> 6] + psum[(t >> 6) + 1];
            if (isA) u[r] = s; else v[r] = s;
        }
        return;
    }
    // blk == 1024: c
    const int d0 = t * 4;
    float4 ww = *(const float4*)&w[d0];
    float4 b1 = *(const float4*)&ba[d0];
    float4 b2 = *(const float4*)&bb[d0];
    float part = ww.x * b1.x * b2.x + ww.y * b1.y * b2.y
               + ww.z * b1.z * b2.z + ww.w * b1.w * b2.w;
#pragma unroll
    for (int off = 32; off; off >>= 1) part += __shfl_down(part, off);
    if ((t & 63) == 0) psum[t >> 6] = part;
    __syncthreads();
    if (t == 0) *c = (psum[0] + psum[1]) + (psum[2] + psum[3]);
}

// ---------------------------------------------------------------------------
// X [16384][1024] f32 -> bf16; also rowdot[r] = sum_d X[r][d]*dvec[d].
// ---------------------------------------------------------------------------
__global__ __launch_bounds__(256) void conv_rows(const float* __restrict__ X,
                                                 const float* __restrict__ dvec,
                                                 unsigned short* __restrict__ out,
                                                 float* __restrict__ rowdot)
{
    __shared__ float psum[4];
    const int t = threadIdx.x;
    const int r = blockIdx.x * 2 + (t >> 7);
    const int c8 = (t & 127) * 8;

    const float* xp = &X[(size_t)r * K_DIM + c8];
    float4 v0 = *(const float4*)xp;
    float4 v1 = *(const float4*)(xp + 4);
    float4 u0 = *(const float4*)&dvec[c8];
    float4 u1 = *(const float4*)&dvec[c8 + 4];
    float part = v0.x * u0.x + v0.y * u0.y + v0.z * u0.z + v0.w * u0.w
               + v1.x * u1.x + v1.y * u1.y + v1.z * u1.z + v1.w * u1.w;

    unsigned short uo[8];
    uo[0] = bf16_bits(v0.x); uo[1] = bf16_bits(v0.y); uo[2] = bf16_bits(v0.z); uo[3] = bf16_bits(v0.w);
    uo[4] = bf16_bits(v1.x); uo[5] = bf16_bits(v1.y); uo[6] = bf16_bits(v1.z); uo[7] = bf16_bits(v1.w);
    *reinterpret_cast<uint4*>(&out[(size_t)r * K_DIM + c8]) = *reinterpret_cast<uint4*>(uo);

#pragma unroll
    for (int off = 32; off; off >>= 1) part += __shfl_down(part, off);
    if ((t & 63) == 0) psum[t >> 6] = part;
    __syncthreads();
    if ((t & 127) == 0) rowdot[r] = psum[(t >> 6)] + psum[(t >> 6) + 1];
}

// ---------------------------------------------------------------------------
// Mt[q][p] = sum_d Wb16[q][d] * Waw[p][d]   (bf16 out, 128x128 tiles)
// ---------------------------------------------------------------------------
__global__ __launch_bounds__(256) void mt_gemm(const __hip_bfloat16* __restrict__ Wb16,
                                               const __hip_bfloat16* __restrict__ Waw,
                                               unsigned short* __restrict__ Mt)
{
    __shared__ __align__(16) unsigned short As[128][32];
    __shared__ __align__(16) unsigned short Bs[128][32];

    const int tid  = threadIdx.x;
    const int lane = tid & 63;
    const int wave = tid >> 6;
    const int q0 = blockIdx.x * 128;
    const int p0 = blockIdx.y * 128;
    const int wr = (wave >> 1) * 64;
    const int wc = (wave & 1) * 64;

    const __hip_bfloat16* Arow = Wb16 + (size_t)q0 * K_DIM;
    const __hip_bfloat16* Brow = Waw + (size_t)p0 * K_DIM;

    f32x4 acc[4][4];
#pragma unroll
    for (int i = 0; i < 4; ++i)
#pragma unroll
        for (int j = 0; j < 4; ++j) acc[i][j] = f32x4{0.f, 0.f, 0.f, 0.f};

    const int lrow = lane & 15;
    const int kq   = (lane >> 4) * 8;

    for (int k0 = 0; k0 < K_DIM; k0 += 32) {
        __syncthreads();
#pragma unroll
        for (int it = 0; it < 2; ++it) {
            const int chunk = (it * 4 + wave) * 64 + lane;
            const int row = chunk >> 2;
            const int col = (chunk & 3) * 8;
            GLOAD16(Arow + (size_t)row * K_DIM + k0 + col,
                    reinterpret_cast<char*>(&As[0][0]) + (it * 4 + wave) * 1024);
        }
#pragma unroll
        for (int it = 0; it < 2; ++it) {
            const int chunk = (it * 4 + wave) * 64 + lane;
            const int row = chunk >> 2;
            const int col = (chunk & 3) * 8;
            GLOAD16(Brow + (size_t)row * K_DIM + k0 + col,
                    reinterpret_cast<char*>(&Bs[0][0]) + (it * 4 + wave) * 1024);
        }
        __syncthreads();

        bf16x8 af[4], bfr[4];
#pragma unroll
        for (int f = 0; f < 4; ++f) {
            af[f]  = *reinterpret_cast<const bf16x8*>(&As[wr + f * 16 + lrow][kq]);
            bfr[f] = *reinterpret_cast<const bf16x8*>(&Bs[wc + f * 16 + lrow][kq]);
        }
#pragma unroll
        for (int i = 0; i < 4; ++i)
#pragma unroll
            for (int j = 0; j < 4; ++j)
                acc[i][j] = __builtin_amdgcn_mfma_f32_16x16x32_bf16(bfr[j], af[i], acc[i][j], 0, 0, 0);
    }

#pragma unroll
    for (int ii = 0; ii < 4; ++ii) {
        const int q = q0 + wr + ii * 16 + lrow;
#pragma unroll
        for (int jj = 0; jj < 4; ++jj) {
            const int pb = p0 + wc + jj * 16 + (lane >> 4) * 4;
            unsigned short uo[4];
            uo[0] = bf16_bits(acc[ii][jj][0]);
            uo[1] = bf16_bits(acc[ii][jj][1]);
            uo[2] = bf16_bits(acc[ii][jj][2]);
            uo[3] = bf16_bits(acc[ii][jj][3]);
            *(ushort4*)&Mt[(size_t)q * K_DIM + pb] = *(ushort4*)uo;
        }
    }
}

// ---------------------------------------------------------------------------
// 8-phase 256x256 GEMM, 0 bank conflicts, LDS-roundtrip coalesced epilogue.
// This round: pre-barrier sched_barrier(0)s removed (compiler free to
// interleave within phases; "memory"-clobbered waitcnts bound all motion).
// ---------------------------------------------------------------------------
__global__ __launch_bounds__(512, 2) void proj_gemm256(
    const __hip_bfloat16* __restrict__ A,   // [M][1024]
    const __hip_bfloat16* __restrict__ Wt,  // [1024][1024]  (row n, col k)
    __hip_bfloat16* __restrict__ out)
{
    __shared__ __align__(16) unsigned short lds[2][4][128 * 64];

    const int tid  = threadIdx.x;
    const int lane = tid & 63;
    const int w    = tid >> 6;
    const int wr   = w >> 2;
    const int wc   = w & 3;
    const int m0 = blockIdx.x * 256;
    const int n0 = blockIdx.y * 256;

    const int c1 = w * 128 + lane, c2 = c1 + 64;
    const int r1 = c1 >> 3, r2 = c2 >> 3;
    const int k1 = (c1 & 7) ^ (r1 & 7);
    const int k2 = (c2 & 7) ^ (r2 & 7);

    const int lrow = lane & 15;
    const int kq0  = (((lane >> 4) + 0) ^ (lane & 7)) * 16;
    const int kq1  = (((lane >> 4) + 4) ^ (lane & 7)) * 16;

#define STG(SRC, RB, KB, BUF, REG)                                               \
    {                                                                            \
        GLOAD16((SRC) + (size_t)((RB) + r1) * K_DIM + (KB) + k1 * 8,             \
                (char*)(&lds[BUF][REG][0]) + w * 2048);                          \
        GLOAD16((SRC) + (size_t)((RB) + r2) * K_DIM + (KB) + k2 * 8,             \
                (char*)(&lds[BUF][REG][0]) + w * 2048 + 1024);                   \
    }

    f32x4 acc[8][4];
#pragma unroll
    for (int i = 0; i < 8; ++i)
#pragma unroll
        for (int j = 0; j < 4; ++j) acc[i][j] = f32x4{0.f, 0.f, 0.f, 0.f};

    STG(A,  m0,       0, 0, 0); STG(A,  m0 + 128,  0, 0, 1);
    STG(Wt, n0,       0, 0, 2); STG(Wt, n0 + 128,  0, 0, 3);
    STG(A,  m0,      64, 1, 0); STG(A,  m0 + 128, 64, 1, 1);
    asm volatile("s_waitcnt vmcnt(4)" ::: "memory");
    __builtin_amdgcn_s_barrier();

#define KTILE(CUR, NXT, T)                                                       \
    {                                                                            \
        const int kb1 = (((T) + 1) & 15) << 6;                                   \
        const int kb2 = (((T) + 2) & 15) << 6;                                   \
        const char* Ab = (const char*)(&lds[CUR][wr][0]);                        \
        const char* Bb = (const char*)(&lds[CUR][2 + (wc >> 1)][0])              \
                         + (wc & 1) * 8192;                                      \
        bf16x8 af[4][2], bfr[4][2];                                              \
        /* ---- phase 1 ---- */                                                  \
        _Pragma("unroll")                                                        \
        for (int mi = 0; mi < 4; ++mi) {                                         \
            af[mi][0] = *(const bf16x8*)(Ab + mi * 2048 + lrow * 128 + kq0);     \
            af[mi][1] = *(const bf16x8*)(Ab + mi * 2048 + lrow * 128 + kq1);     \
        }                                                                        \
        _Pragma("unroll")                                                        \
        for (int nj = 0; nj < 2; ++nj) {                                         \
            bfr[nj][0] = *(const bf16x8*)(Bb + nj * 2048 + lrow * 128 + kq0);    \
            bfr[nj][1] = *(const bf16x8*)(Bb + nj * 2048 + lrow * 128 + kq1);    \
        }                                                                        \
        STG(Wt, n0, kb1, NXT, 2);                                                \
        __builtin_amdgcn_s_barrier();                                            \
        asm volatile("s_waitcnt lgkmcnt(0)" ::: "memory");                       \
        __builtin_amdgcn_sched_barrier(0);                                       \
        __builtin_amdgcn_s_setprio(1);                                           \
        _Pragma("unroll")                                                        \
        for (int mi = 0; mi < 4; ++mi)                                           \
            _Pragma("unroll")                                                    \
            for (int nj = 0; nj < 2; ++nj) {                                     \
                acc[mi][nj] = __builtin_amdgcn_mfma_f32_16x16x32_bf16(           \
                    bfr[nj][0], af[mi][0], acc[mi][nj], 0, 0, 0);                \
                acc[mi][nj] = __builtin_amdgcn_mfma_f32_16x16x32_bf16(           \
                    bfr[nj][1], af[mi][1], acc[mi][nj], 0, 0, 0);                \
            }                                                                    \
        __builtin_amdgcn_s_setprio(0);                                           \
        __builtin_amdgcn_s_barrier();                                            \
        /* ---- phase 2 ---- */                                                  \
        _Pragma("unroll")                                                        \
        for (int nj = 2; nj < 4; ++nj) {                                         \
            bfr[nj][0] = *(const bf16x8*)(Bb + nj * 2048 + lrow * 128 + kq0);    \
            bfr[nj][1] = *(const bf16x8*)(Bb + nj * 2048 + lrow * 128 + kq1);    \
        }                                                                        \
        STG(Wt, n0 + 128, kb1, NXT, 3);                                          \
        __builtin_amdgcn_s_barrier();                                            \
        asm volatile("s_waitcnt lgkmcnt(0)" ::: "memory");                       \
        __builtin_amdgcn_sched_barrier(0);                                       \
        __builtin_amdgcn_s_setprio(1);                                           \
        _Pragma("unroll")                                                        \
        for (int mi = 0; mi < 4; ++mi)                                           \
            _Pragma("unroll")                                                    \
            for (int nj = 2; nj < 4; ++nj) {                                     \
                acc[mi][nj] = __builtin_amdgcn_mfma_f32_16x16x32_bf16(           \
                    bfr[nj][0], af[mi][0], acc[mi][nj], 0, 0, 0);                \
                acc[mi][nj] = __builtin_amdgcn_mfma_f32_16x16x32_bf16(           \
                    bfr[nj][1], af[mi][1], acc[mi][nj], 0, 0, 0);                \
            }                                                                    \
        __builtin_amdgcn_s_setprio(0);                                           \
        __builtin_amdgcn_s_barrier();                                            \
        /* ---- phase 3 ---- */                                                  \
        _Pragma("unroll")                                                        \
        for (int mi = 0; mi < 4; ++mi) {                                         \
            af[mi][0] = *(const bf16x8*)(Ab + 8192 + mi * 2048 + lrow * 128 + kq0);\
            af[mi][1] = *(const bf16x8*)(Ab + 8192 + mi * 2048 + lrow * 128 + kq1);\
        }                                                                        \
        __builtin_amdgcn_s_barrier();                                            \
        asm volatile("s_waitcnt lgkmcnt(0)" ::: "memory");                       \
        __builtin_amdgcn_sched_barrier(0);                                       \
        __builtin_amdgcn_s_setprio(1);                                           \
        _Pragma("unroll")                                                        \
        for (int mi = 0; mi < 4; ++mi)                                           \
            _Pragma("unroll")                                                    \
            for (int nj = 0; nj < 2; ++nj) {                                     \
                acc[4 + mi][nj] = __builtin_amdgcn_mfma_f32_16x16x32_bf16(       \
                    bfr[nj][0], af[mi][0], acc[4 + mi][nj], 0, 0, 0);            \
                acc[4 + mi][nj] = __builtin_amdgcn_mfma_f32_16x16x32_bf16(       \
                    bfr[nj][1], af[mi][1], acc[4 + mi][nj], 0, 0, 0);            \
            }                                                                    \
        __builtin_amdgcn_s_setprio(0);                                           \
        __builtin_amdgcn_s_barrier();                                            \
        /* ---- phase 4 ---- */                                                  \
        STG(A, m0,       kb2, CUR, 0);                                           \
        STG(A, m0 + 128, kb2, CUR, 1);                                           \
        __builtin_amdgcn_s_barrier();                                            \
        __builtin_amdgcn_s_setprio(1);                                           \
        _Pragma("unroll")                                                        \
        for (int mi = 0; mi < 4; ++mi)                                           \
            _Pragma("unroll")                                                    \
            for (int nj = 2; nj < 4; ++nj) {                                     \
                acc[4 + mi][nj] = __builtin_amdgcn_mfma_f32_16x16x32_bf16(       \
                    bfr[nj][0], af[mi][0], acc[4 + mi][nj], 0, 0, 0);            \
                acc[4 + mi][nj] = __builtin_amdgcn_mfma_f32_16x16x32_bf16(       \
                    bfr[nj][1], af[mi][1], acc[4 + mi][nj], 0, 0, 0);            \
            }                                                                    \
        __builtin_amdgcn_s_setprio(0);                                           \
        asm volatile("s_waitcnt vmcnt(4)" ::: "memory");                         \
        __builtin_amdgcn_s_barrier();                                            \
    }

    for (int tt = 0; tt < 8; ++tt) {
        const int t0 = tt * 2;
        KTILE(0, 1, t0);
        KTILE(1, 0, t0 + 1);
    }
#undef KTILE
#undef STG

    // ---- coalesced epilogue via LDS roundtrip ----
    asm volatile("s_waitcnt vmcnt(0)" ::: "memory");
    __builtin_amdgcn_s_barrier();
    char* eb = (char*)(&lds[0][0][0]);
#pragma unroll
    for (int mi8 = 0; mi8 < 8; ++mi8) {
        const int ml = wr * 128 + (mi8 >> 2) * 64 + (mi8 & 3) * 16 + lrow;
#pragma unroll
        for (int nj = 0; nj < 4; ++nj) {
            const int nl = wc * 64 + nj * 16 + (lane >> 4) * 4;
            unsigned short uo[4];
            uo[0] = bf16_bits(acc[mi8][nj][0]);
            uo[1] = bf16_bits(acc[mi8][nj][1]);
            uo[2] = bf16_bits(acc[mi8][nj][2]);
            uo[3] = bf16_bits(acc[mi8][nj][3]);
            const int vv = nl >> 3;
            *(ushort4*)(eb + ml * 512 + ((vv ^ (ml & 7)) * 16) + ((nl >> 2) & 1) * 8)
                = *(ushort4*)uo;
        }
    }
    __syncthreads();
#pragma unroll
    for (int p = 0; p < 2; ++p) {
        const int ml = p * 128 + (tid >> 2);
#pragma unroll
        for (int it = 0; it < 8; ++it) {
            const int vv = it * 4 + (tid & 3);
            uint4 val = *(const uint4*)(eb + ml * 512 + ((vv ^ (ml & 7)) * 16));
            *(uint4*)&out[(size_t)(m0 + ml) * K_DIM + n0 + vv * 8] = val;
        }
    }
}

// ---------------------------------------------------------------------------
// Scores (128x128 tiles) + fused exp. 1-D grid: id = b + 64*q -> 4 blocks of
// batch b are == b (mod 8) -> same XCD -> L2 panel reuse.
// ---------------------------------------------------------------------------
__global__ __launch_bounds__(256) void score_gemm(const __hip_bfloat16* __restrict__ T,
                                                  const __hip_bfloat16* __restrict__ Bbf,
                                                  const float* __restrict__ alpha,
                                                  const float* __restrict__ beta,
                                                  const float* __restrict__ cptr,
                                                  const float* __restrict__ wbias,
                                                  float* __restrict__ out,
                                                  float* __restrict__ partials)
{
    __shared__ __align__(16) unsigned short As[128][32];
    __shared__ __align__(16) unsigned short Bs[128][32];
    __shared__ float psum[4];

    const int tid  = threadIdx.x;
    const int lane = tid & 63;
    const int wave = tid >> 6;
    const int b  = blockIdx.x & 63;
    const int q  = blockIdx.x >> 6;       // 0..3
    const int i0 = (q >> 1) * 128;
    const int j0 = (q & 1) * 128;
    const int wr = (wave >> 1) * 64;
    const int wc = (wave & 1) * 64;

    const __hip_bfloat16* Arow = T + (size_t)(b * SEQ + i0) * K_DIM;
    const __hip_bfloat16* Brow = Bbf + (size_t)(b * SEQ + j0) * K_DIM;

    f32x4 acc[4][4];
#pragma unroll
    for (int i = 0; i < 4; ++i)
#pragma unroll
        for (int j = 0; j < 4; ++j) acc[i][j] = f32x4{0.f, 0.f, 0.f, 0.f};

    const int lrow = lane & 15;
    const int kq   = (lane >> 4) * 8;

    for (int k0 = 0; k0 < K_DIM; k0 += 32) {
        __syncthreads();
#pragma unroll
        for (int it = 0; it < 2; ++it) {
            const int chunk = (it * 4 + wave) * 64 + lane;
            const int row = chunk >> 2;
            const int col = (chunk & 3) * 8;
            GLOAD16(Arow + (size_t)row * K_DIM + k0 + col,
                    reinterpret_cast<char*>(&As[0][0]) + (it * 4 + wave) * 1024);
        }
#pragma unroll
        for (int it = 0; it < 2; ++it) {
            const int chunk = (it * 4 + wave) * 64 + lane;
            const int row = chunk >> 2;
            const int col = (chunk & 3) * 8;
            GLOAD16(Brow + (size_t)row * K_DIM + k0 + col,
                    reinterpret_cast<char*>(&Bs[0][0]) + (it * 4 + wave) * 1024);
        }
        __syncthreads();

        bf16x8 af[4], bfr[4];
#pragma unroll
        for (int f = 0; f < 4; ++f) {
            af[f]  = *reinterpret_cast<const bf16x8*>(&As[wr + f * 16 + lrow][kq]);
            bfr[f] = *reinterpret_cast<const bf16x8*>(&Bs[wc + f * 16 + lrow][kq]);
        }
#pragma unroll
        for (int i = 0; i < 4; ++i)
#pragma unroll
            for (int j = 0; j < 4; ++j)
                acc[i][j] = __builtin_amdgcn_mfma_f32_16x16x32_bf16(bfr[j], af[i], acc[i][j], 0, 0, 0);
    }

    const float cwb = *cptr + *wbias;
    float lsum = 0.f;
#pragma unroll
    for (int ii = 0; ii < 4; ++ii) {
        const int i = i0 + wr + ii * 16 + lrow;
        const float av = alpha[b * SEQ + i] + cwb;
#pragma unroll
        for (int jj = 0; jj < 4; ++jj) {
            const int jb = j0 + wc + jj * 16 + (lane >> 4) * 4;
            const float4 bv = *(const float4*)&beta[b * SEQ + jb];
            float4 e;
            e.x = __expf(acc[ii][jj][0] + av + bv.x);
            e.y = __expf(acc[ii][jj][1] + av + bv.y);
            e.z = __expf(acc[ii][jj][2] + av + bv.z);
            e.w = __expf(acc[ii][jj][3] + av + bv.w);
            lsum += (e.x + e.y) + (e.z + e.w);
            *(float4*)&out[(size_t)b * (SEQ * SEQ) + (size_t)i * SEQ + jb] = e;
        }
    }
#pragma unroll
    for (int off = 32; off; off >>= 1) lsum += __shfl_down(lsum, off);
    if (lane == 0) psum[wave] = lsum;
    __syncthreads();
    if (tid == 0)
        partials[b * 4 + q] = (psum[0] + psum[1]) + (psum[2] + psum[3]);
}

// ---------------------------------------------------------------------------
// Normalize: out[b][:] *= 1/sum_b   (4 partials per batch, fixed order)
// ---------------------------------------------------------------------------
__global__ __launch_bounds__(1024) void normalize_k(float* __restrict__ s,
                                                    const float* __restrict__ partials)
{
    const int b    = blockIdx.x >> 2;
    const int part = blockIdx.x & 3;
    const float inv = 1.0f / (((partials[b * 4 + 0] + partials[b * 4 + 1]) +
                               partials[b * 4 + 2]) + partials[b * 4 + 3]);
    float4* p4 = reinterpret_cast<float4*>(s + (size_t)b * (SEQ * SEQ));
    const int base = part * 4096;
#pragma unroll
    for (int it = 0; it < 4; ++it) {
        const int i = base + it * 1024 + threadIdx.x;
        float4 v = p4[i];
        v.x *= inv; v.y *= inv; v.z *= inv; v.w *= inv;
        p4[i] = v;
    }
}

extern "C" void kernel_launch(void* const* d_in, const int* in_sizes, int n_in,
                              void* d_out, int out_size, void* d_ws, size_t ws_size,
                              hipStream_t stream)
{
    const float* a     = (const float*)d_in[0];
    const float* b     = (const float*)d_in[1];
    const float* Wa    = (const float*)d_in[2];
    const float* ba    = (const float*)d_in[3];
    const float* Wb    = (const float*)d_in[4];
    const float* bb    = (const float*)d_in[5];
    const float* w     = (const float*)d_in[6];
    const float* wbias = (const float*)d_in[7];
    float* out = (float*)d_out;

    char* wsb = (char*)d_ws;
    unsigned short* Waw   = (unsigned short*)(wsb);                       // 2MB
    unsigned short* Wb16  = (unsigned short*)(wsb + (size_t)2097152);     // 2MB
    unsigned short* Mt    = (unsigned short*)(wsb + (size_t)4194304);     // 2MB
    float* u              = (float*)(wsb + (size_t)6291456);              // 4KB
    float* v              = (float*)(wsb + (size_t)6291456 + 4096);       // 4KB
    float* c              = (float*)(wsb + (size_t)6291456 + 8192);       // 4B
    float* alpha          = (float*)(wsb + (size_t)6291456 + 16384);      // 64KB
    float* beta           = (float*)(wsb + (size_t)6291456 + 16384 + 65536); // 64KB
    float* partials       = (float*)(wsb + (size_t)6291456 + 16384 + 131072); // 1KB
    unsigned short* ab16  = (unsigned short*)(wsb + (size_t)8388608);     // 32MB (a then b)
    unsigned short* Tbuf  = (unsigned short*)(wsb + (size_t)41943040);    // 32MB

    // 1. weight converts + u/v/c (one launch)
    prep<<<1025, 256, 0, stream>>>(Wa, Wb, w, ba, bb, Waw, Wb16, u, v, c);
    // 2. Mt = (Wa*w) . Wb^T, transposed-stored [q][p]
    mt_gemm<<<dim3(8, 8), 256, 0, stream>>>((const __hip_bfloat16*)Wb16,
                                            (const __hip_bfloat16*)Waw, Mt);
    // 3. a -> bf16 (+alpha = a.u)
    conv_rows<<<M_PROJ / 2, 256, 0, stream>>>(a, u, ab16, alpha);
    // 4. T = a_bf16 @ Mt^T
    const dim3 pgrid(M_PROJ / 256, K_DIM / 256);
    proj_gemm256<<<pgrid, 512, 0, stream>>>((const __hip_bfloat16*)ab16,
                                            (const __hip_bfloat16*)Mt,
                                            (__hip_bfloat16*)Tbuf);
    // 5. b -> bf16 (+beta = b.v)  — reuses ab16
    conv_rows<<<M_PROJ / 2, 256, 0, stream>>>(b, v, ab16, beta);
    // 6. scores + exp + partials  (XCD-grouped 1-D grid)
    score_gemm<<<256, 256, 0, stream>>>((const __hip_bfloat16*)Tbuf,
                                        (const __hip_bfloat16*)ab16,
                                        alpha, beta, c, wbias, out, partials);
    // 7. normalize
    normalize_k<<<NBATCH * 4, 1024, 0, stream>>>(out, partials);
}